// Round 1
// baseline (332.098 us; speedup 1.0000x reference)
//
#include <hip/hip_runtime.h>
#include <math.h>

// ---------------------------------------------------------------------------
// AngleEncodingQuantumNet: conv1+BN+relu+pool -> conv2+BN+relu+pool -> fc1
// (tanh) -> sel -> 10-qubit RY/CZ circuit -> post1(relu) -> post2.
// Train-mode BN => two-pass convs (stats pass, then fused pass).
// All f32 compute; BN statistics reduced in f64 for accuracy.
// ---------------------------------------------------------------------------

#define BATCH 2048
#define PI_F 3.14159265358979323846f

__device__ __forceinline__ float wave_reduce_add(float v) {
#pragma unroll
  for (int off = 32; off >= 1; off >>= 1) v += __shfl_xor(v, off, 64);
  return v;
}

// ---------------- conv1: stats pass ----------------------------------------
// block = one image b; tasks = 16 oc x 28 rows; shifting 3x3 window.
__global__ __launch_bounds__(256) void k_conv1_stats(
    const float* __restrict__ x, const float* __restrict__ cw,
    const float* __restrict__ cb, float* __restrict__ part1) {
  const int b = blockIdx.x;
  const int t = threadIdx.x;
  __shared__ float xs[30][33];
  __shared__ float ws[160];
  __shared__ float redS[16][28];
  __shared__ float redQ[16][28];
  for (int i = t; i < 30 * 33; i += 256) (&xs[0][0])[i] = 0.f;
  if (t < 144) ws[t] = cw[t];
  else if (t < 160) ws[t] = cb[t - 144];
  __syncthreads();
  const float* xb = x + b * 784;
  for (int i = t; i < 784; i += 256) xs[1 + i / 28][1 + (i % 28)] = xb[i];
  __syncthreads();
  for (int task = t; task < 448; task += 256) {
    const int oc = task / 28;
    const int row = task - oc * 28;
    float wk[9];
#pragma unroll
    for (int k = 0; k < 9; ++k) wk[k] = ws[oc * 9 + k];
    const float bc = ws[144 + oc];
    float A0 = xs[row][0], A1 = xs[row][1];
    float B0 = xs[row + 1][0], B1 = xs[row + 1][1];
    float C0 = xs[row + 2][0], C1 = xs[row + 2][1];
    float s = 0.f, q = 0.f;
#pragma unroll 4
    for (int xx = 0; xx < 28; ++xx) {
      float A2 = xs[row][xx + 2], B2 = xs[row + 1][xx + 2], C2 = xs[row + 2][xx + 2];
      float acc = bc;
      acc = fmaf(wk[0], A0, acc); acc = fmaf(wk[1], A1, acc); acc = fmaf(wk[2], A2, acc);
      acc = fmaf(wk[3], B0, acc); acc = fmaf(wk[4], B1, acc); acc = fmaf(wk[5], B2, acc);
      acc = fmaf(wk[6], C0, acc); acc = fmaf(wk[7], C1, acc); acc = fmaf(wk[8], C2, acc);
      s += acc; q = fmaf(acc, acc, q);
      A0 = A1; A1 = A2; B0 = B1; B1 = B2; C0 = C1; C1 = C2;
    }
    redS[oc][row] = s;
    redQ[oc][row] = q;
  }
  __syncthreads();
  if (t < 32) {
    const int c = t >> 1;
    float acc = 0.f;
    if (t & 1) {
#pragma unroll 4
      for (int r = 0; r < 28; ++r) acc += redQ[c][r];
    } else {
#pragma unroll 4
      for (int r = 0; r < 28; ++r) acc += redS[c][r];
    }
    part1[b * 32 + t] = acc;  // layout [b][c*2 + {sum,sq}]
  }
}

// ---------------- BN stats fold (both layers) -------------------------------
__global__ __launch_bounds__(256) void k_bnstat(
    const float* __restrict__ part, const float* __restrict__ g,
    const float* __restrict__ bb, float* __restrict__ stats,
    int nch, int nblk, double invN) {
  const int c = blockIdx.x;
  const int t = threadIdx.x;
  const int stride = nch * 2;
  double ls = 0.0, lq = 0.0;
  for (int i = t; i < nblk; i += 256) {
    ls += (double)part[i * stride + c * 2];
    lq += (double)part[i * stride + c * 2 + 1];
  }
#pragma unroll
  for (int off = 32; off >= 1; off >>= 1) {
    ls += __shfl_xor(ls, off, 64);
    lq += __shfl_xor(lq, off, 64);
  }
  __shared__ double rs[4], rq[4];
  if ((t & 63) == 0) { rs[t >> 6] = ls; rq[t >> 6] = lq; }
  __syncthreads();
  if (t == 0) {
    double S = rs[0] + rs[1] + rs[2] + rs[3];
    double Q = rq[0] + rq[1] + rq[2] + rq[3];
    double mean = S * invN;
    double var = Q * invN - mean * mean;
    double inv = 1.0 / sqrt(var + 1e-5);
    double sc = (double)g[c] * inv;
    stats[c * 2] = (float)sc;
    stats[c * 2 + 1] = (float)((double)bb[c] - mean * sc);
  }
}

// ---------------- conv1: fused BN+relu+pool pass ----------------------------
__global__ __launch_bounds__(256) void k_conv1_fused(
    const float* __restrict__ x, const float* __restrict__ cw,
    const float* __restrict__ cb, const float* __restrict__ stats1,
    float* __restrict__ h1) {
  const int b = blockIdx.x;
  const int t = threadIdx.x;
  __shared__ float xs[30][33];
  __shared__ float ws[160];
  for (int i = t; i < 30 * 33; i += 256) (&xs[0][0])[i] = 0.f;
  if (t < 144) ws[t] = cw[t];
  else if (t < 160) ws[t] = cb[t - 144];
  __syncthreads();
  const float* xb = x + b * 784;
  for (int i = t; i < 784; i += 256) xs[1 + i / 28][1 + (i % 28)] = xb[i];
  __syncthreads();
  if (t < 224) {
    const int oc = t / 14;
    const int pr = t - oc * 14;
    float wk[9];
#pragma unroll
    for (int k = 0; k < 9; ++k) wk[k] = ws[oc * 9 + k];
    const float bc = ws[144 + oc];
    const float scale = stats1[oc * 2], shift = stats1[oc * 2 + 1];
    const int r0 = 2 * pr;
    float A0 = xs[r0][0],     A1 = xs[r0][1];
    float B0 = xs[r0 + 1][0], B1 = xs[r0 + 1][1];
    float C0 = xs[r0 + 2][0], C1 = xs[r0 + 2][1];
    float D0 = xs[r0 + 3][0], D1 = xs[r0 + 3][1];
    float* hout = h1 + ((b * 16 + oc) * 14 + pr) * 14;
    float pmax = 0.f;
#pragma unroll 4
    for (int xx = 0; xx < 28; ++xx) {
      float A2 = xs[r0][xx + 2], B2 = xs[r0 + 1][xx + 2];
      float C2 = xs[r0 + 2][xx + 2], D2 = xs[r0 + 3][xx + 2];
      float c0 = bc, c1 = bc;
      c0 = fmaf(wk[0], A0, c0); c0 = fmaf(wk[1], A1, c0); c0 = fmaf(wk[2], A2, c0);
      c0 = fmaf(wk[3], B0, c0); c0 = fmaf(wk[4], B1, c0); c0 = fmaf(wk[5], B2, c0);
      c0 = fmaf(wk[6], C0, c0); c0 = fmaf(wk[7], C1, c0); c0 = fmaf(wk[8], C2, c0);
      c1 = fmaf(wk[0], B0, c1); c1 = fmaf(wk[1], B1, c1); c1 = fmaf(wk[2], B2, c1);
      c1 = fmaf(wk[3], C0, c1); c1 = fmaf(wk[4], C1, c1); c1 = fmaf(wk[5], C2, c1);
      c1 = fmaf(wk[6], D0, c1); c1 = fmaf(wk[7], D1, c1); c1 = fmaf(wk[8], D2, c1);
      float e0 = fmaxf(fmaf(scale, c0, shift), 0.f);
      float e1 = fmaxf(fmaf(scale, c1, shift), 0.f);
      float m = fmaxf(e0, e1);
      if ((xx & 1) == 0) pmax = m;
      else hout[xx >> 1] = fmaxf(pmax, m);
      A0 = A1; A1 = A2; B0 = B1; B1 = B2; C0 = C1; C1 = C2; D0 = D1; D1 = D2;
    }
  }
}

// ---------------- conv2: stats pass / fused pass (template) -----------------
// block = one image b. thread: oc = t>>3, j = t&7 (row-pair / pooled-row),
// j==7 idle for compute. Padded input tile [16][16][20] (b128-aligned,
// <=2-way bank aliasing); weights [ic][oc][12] for aligned float4 reads.
template <bool STATS>
__global__ __launch_bounds__(256, 2) void k_conv2(
    const float* __restrict__ h1, const float* __restrict__ cw,
    const float* __restrict__ cb, const float* __restrict__ stats2,
    float* __restrict__ part2, float* __restrict__ h2) {
  const int b = blockIdx.x;
  const int t = threadIdx.x;
  __shared__ float ins[16 * 16 * 20];
  __shared__ float w4[16 * 32 * 12];
  __shared__ float red[64];
  for (int i = t; i < 16 * 16 * 20; i += 256) ins[i] = 0.f;
  for (int i = t; i < 16 * 32 * 12; i += 256) w4[i] = 0.f;
  __syncthreads();
  const float* h1b = h1 + b * 3136;
  for (int i = t; i < 3136; i += 256) {
    int ic = i / 196, p = i - ic * 196;
    int y = p / 14, xx = p - y * 14;
    ins[(ic * 16 + 1 + y) * 20 + 1 + xx] = h1b[i];
  }
  for (int i = t; i < 4608; i += 256) {
    int ic = i / 288, jj = i - ic * 288;
    int oc = jj / 9, k = jj - oc * 9;
    w4[(ic * 32 + oc) * 12 + k] = cw[oc * 144 + ic * 9 + k];
  }
  __syncthreads();
  const int oc = t >> 3;
  const int j = t & 7;
  const float bc = cb[oc];
  float v0[14], v1[14];
#pragma unroll
  for (int i = 0; i < 14; ++i) { v0[i] = bc; v1[i] = bc; }
  if (j < 7) {
    const int rbase = 2 * j;
    for (int ic = 0; ic < 16; ++ic) {
      const float4* wp = (const float4*)&w4[(ic * 32 + oc) * 12];
      float4 wa = wp[0], wb = wp[1], wc = wp[2];
      float wk[9] = {wa.x, wa.y, wa.z, wa.w, wb.x, wb.y, wb.z, wb.w, wc.x};
      const float* rowp = &ins[(ic * 16 + rbase) * 20];
      float R0[16], R1[16], R2[16], R3[16];
#pragma unroll
      for (int q = 0; q < 4; ++q) {
        *(float4*)&R0[q * 4] = ((const float4*)(rowp))[q];
        *(float4*)&R1[q * 4] = ((const float4*)(rowp + 20))[q];
        *(float4*)&R2[q * 4] = ((const float4*)(rowp + 40))[q];
        *(float4*)&R3[q * 4] = ((const float4*)(rowp + 60))[q];
      }
#pragma unroll
      for (int xx = 0; xx < 14; ++xx) {
        float a0 = v0[xx], a1 = v1[xx];
        a0 = fmaf(wk[0], R0[xx], a0); a0 = fmaf(wk[1], R0[xx + 1], a0); a0 = fmaf(wk[2], R0[xx + 2], a0);
        a0 = fmaf(wk[3], R1[xx], a0); a0 = fmaf(wk[4], R1[xx + 1], a0); a0 = fmaf(wk[5], R1[xx + 2], a0);
        a0 = fmaf(wk[6], R2[xx], a0); a0 = fmaf(wk[7], R2[xx + 1], a0); a0 = fmaf(wk[8], R2[xx + 2], a0);
        a1 = fmaf(wk[0], R1[xx], a1); a1 = fmaf(wk[1], R1[xx + 1], a1); a1 = fmaf(wk[2], R1[xx + 2], a1);
        a1 = fmaf(wk[3], R2[xx], a1); a1 = fmaf(wk[4], R2[xx + 1], a1); a1 = fmaf(wk[5], R2[xx + 2], a1);
        a1 = fmaf(wk[6], R3[xx], a1); a1 = fmaf(wk[7], R3[xx + 1], a1); a1 = fmaf(wk[8], R3[xx + 2], a1);
        v0[xx] = a0; v1[xx] = a1;
      }
    }
  }
  if (STATS) {
    float s = 0.f, q = 0.f;
    if (j < 7) {
#pragma unroll
      for (int i = 0; i < 14; ++i) {
        s += v0[i] + v1[i];
        q = fmaf(v0[i], v0[i], q);
        q = fmaf(v1[i], v1[i], q);
      }
    }
#pragma unroll
    for (int off = 1; off <= 4; off <<= 1) {
      s += __shfl_xor(s, off, 64);
      q += __shfl_xor(q, off, 64);
    }
    if (j == 0) { red[oc * 2] = s; red[oc * 2 + 1] = q; }
    __syncthreads();
    if (t < 64) part2[b * 64 + t] = red[t];
  } else {
    if (j < 7) {
      const float scale = stats2[oc * 2], shift = stats2[oc * 2 + 1];
      float* hp = h2 + b * 1568 + oc * 49 + j * 7;
#pragma unroll
      for (int px = 0; px < 7; ++px) {
        float e00 = fmaxf(fmaf(scale, v0[2 * px], shift), 0.f);
        float e01 = fmaxf(fmaf(scale, v0[2 * px + 1], shift), 0.f);
        float e10 = fmaxf(fmaf(scale, v1[2 * px], shift), 0.f);
        float e11 = fmaxf(fmaf(scale, v1[2 * px + 1], shift), 0.f);
        hp[px] = fmaxf(fmaxf(e00, e01), fmaxf(e10, e11));
      }
    }
  }
}

// ---------------- fc1 GEMM + tanh -------------------------------------------
// C[m,n] = tanh(sum_k A[m,k] * W[n,k] + bias[n]); A=[2048][1568], W=[784][1568]
__global__ __launch_bounds__(256) void k_fc1(
    const float* __restrict__ A, const float* __restrict__ W,
    const float* __restrict__ bias, float* __restrict__ feats) {
  __shared__ float As[16][68];
  __shared__ float Ws[16][68];
  const int t = threadIdx.x;
  const int bx = blockIdx.x;   // 13 n-tiles
  const int by = blockIdx.y;   // 32 m-tiles
  const int row = t >> 2, kq = t & 3;
  const int tx = t & 15, ty = t >> 4;
  const int m0 = by * 64, n0 = bx * 64;
  float acc[4][4];
#pragma unroll
  for (int i = 0; i < 4; ++i)
#pragma unroll
    for (int jj = 0; jj < 4; ++jj) acc[i][jj] = 0.f;
  const int nrow = n0 + row;
  const bool wok = nrow < 784;
  for (int k0 = 0; k0 < 1568; k0 += 16) {
    float4 av = *(const float4*)&A[(m0 + row) * 1568 + k0 + kq * 4];
    float4 wv = wok ? *(const float4*)&W[nrow * 1568 + k0 + kq * 4]
                    : make_float4(0.f, 0.f, 0.f, 0.f);
    __syncthreads();
    As[kq * 4 + 0][row] = av.x; As[kq * 4 + 1][row] = av.y;
    As[kq * 4 + 2][row] = av.z; As[kq * 4 + 3][row] = av.w;
    Ws[kq * 4 + 0][row] = wv.x; Ws[kq * 4 + 1][row] = wv.y;
    Ws[kq * 4 + 2][row] = wv.z; Ws[kq * 4 + 3][row] = wv.w;
    __syncthreads();
#pragma unroll
    for (int kk = 0; kk < 16; ++kk) {
      float4 a4 = *(const float4*)&As[kk][ty * 4];
      float4 w4v = *(const float4*)&Ws[kk][tx * 4];
      float aa[4] = {a4.x, a4.y, a4.z, a4.w};
      float ww[4] = {w4v.x, w4v.y, w4v.z, w4v.w};
#pragma unroll
      for (int i = 0; i < 4; ++i)
#pragma unroll
        for (int jj = 0; jj < 4; ++jj) acc[i][jj] = fmaf(aa[i], ww[jj], acc[i][jj]);
    }
  }
#pragma unroll
  for (int i = 0; i < 4; ++i) {
    const int m = m0 + ty * 4 + i;
#pragma unroll
    for (int jj = 0; jj < 4; ++jj) {
      const int n = n0 + tx * 4 + jj;
      if (n < 784) feats[m * 784 + n] = tanhf(acc[i][jj] + bias[n]);
    }
  }
}

// ---------------- sel: feats[2048][784] @ sel_w[10][784]^T + b --------------
__global__ __launch_bounds__(256) void k_sel(
    const float* __restrict__ feats, const float* __restrict__ sw,
    const float* __restrict__ sb, float* __restrict__ selv) {
  const int wid = (blockIdx.x << 2) + (threadIdx.x >> 6);
  const int lane = threadIdx.x & 63;
  const float* f = feats + wid * 784;
  float acc[10];
#pragma unroll
  for (int i = 0; i < 10; ++i) acc[i] = 0.f;
  for (int k = lane; k < 784; k += 64) {
    const float fv = f[k];
#pragma unroll
    for (int i = 0; i < 10; ++i) acc[i] = fmaf(fv, sw[i * 784 + k], acc[i]);
  }
#pragma unroll
  for (int i = 0; i < 10; ++i) acc[i] = wave_reduce_add(acc[i]);
  if (lane == 0) {
#pragma unroll
    for (int i = 0; i < 10; ++i) selv[wid * 10 + i] = acc[i] + sb[i];
  }
}

// ---------------- 10-qubit statevector circuit ------------------------------
// One wave per batch element. 1024 real amps; idx = lane*16 + r.
// Wires 0..3 = register bits (in-lane), wires 4..9 = lane bits (shfl_xor).
template <int W>
__device__ __forceinline__ void ry_gate(float (&a)[16], int lane, float th) {
  float s, c;
  sincosf(0.5f * th, &s, &c);
  if (W < 4) {
    const int st = 1 << W;
#pragma unroll
    for (int r = 0; r < 16; ++r) {
      if (!(r & st)) {
        float lo = a[r], hi = a[r + st];
        a[r] = fmaf(c, lo, -s * hi);
        a[r + st] = fmaf(s, lo, c * hi);
      }
    }
  } else {
    const int m = 1 << (W - 4);
    const float sg = (lane & m) ? s : -s;
#pragma unroll
    for (int r = 0; r < 16; ++r) {
      float other = __shfl_xor(a[r], m, 64);
      a[r] = fmaf(c, a[r], sg * other);
    }
  }
}

#define RY10(EXPR)                                                   \
  {                                                                  \
    ry_gate<0>(a, lane, EXPR(0)); ry_gate<1>(a, lane, EXPR(1));      \
    ry_gate<2>(a, lane, EXPR(2)); ry_gate<3>(a, lane, EXPR(3));      \
    ry_gate<4>(a, lane, EXPR(4)); ry_gate<5>(a, lane, EXPR(5));      \
    ry_gate<6>(a, lane, EXPR(6)); ry_gate<7>(a, lane, EXPR(7));      \
    ry_gate<8>(a, lane, EXPR(8)); ry_gate<9>(a, lane, EXPR(9));      \
  }

__global__ __launch_bounds__(256) void k_quantum(
    const float* __restrict__ selv, const float* __restrict__ qp,
    float* __restrict__ qout) {
  const int b = (blockIdx.x << 2) + (threadIdx.x >> 6);
  const int lane = threadIdx.x & 63;
  float a[16];
#pragma unroll
  for (int r = 0; r < 16; ++r) a[r] = 0.f;
  if (lane == 0) a[0] = 1.f;
  // combined CZ-chain sign (all 9 CZs are diagonal & commute): constant/layer
  float czs[16];
#pragma unroll
  for (int r = 0; r < 16; ++r) {
    int idx = (lane << 4) | r;
    czs[r] = (__popc(idx & (idx >> 1)) & 1) ? -1.f : 1.f;
  }
  const float* sp = selv + b * 10;
#define ENC(i) (sp[i] * PI_F)
  RY10(ENC)
#undef ENC
  for (int layer = 0; layer < 3; ++layer) {
    const float* lp = qp + layer * 10;
#define LAY(i) (lp[i])
    RY10(LAY)
#undef LAY
#pragma unroll
    for (int r = 0; r < 16; ++r) a[r] *= czs[r];
  }
  float p[16];
  float lt = 0.f;
#pragma unroll
  for (int r = 0; r < 16; ++r) { p[r] = a[r] * a[r]; lt += p[r]; }
  float z[10];
#pragma unroll
  for (int w = 0; w < 4; ++w) {
    float v = 0.f;
#pragma unroll
    for (int r = 0; r < 16; ++r) v += ((r >> w) & 1) ? -p[r] : p[r];
    z[w] = v;
  }
#pragma unroll
  for (int w = 4; w < 10; ++w) z[w] = ((lane >> (w - 4)) & 1) ? -lt : lt;
#pragma unroll
  for (int w = 0; w < 10; ++w) z[w] = wave_reduce_add(z[w]);
  if (lane == 0) {
#pragma unroll
    for (int w = 0; w < 10; ++w) qout[b * 10 + w] = z[w];
  }
}

// ---------------- post layers ------------------------------------------------
__global__ __launch_bounds__(256) void k_post(
    const float* __restrict__ qout, const float* __restrict__ w1,
    const float* __restrict__ b1, const float* __restrict__ w2,
    const float* __restrict__ b2, float* __restrict__ out) {
  const int b = blockIdx.x * 256 + threadIdx.x;
  float qv[10];
#pragma unroll
  for (int i = 0; i < 10; ++i) qv[i] = qout[b * 10 + i];
  float h[32];
#pragma unroll
  for (int jj = 0; jj < 32; ++jj) {
    float s = b1[jj];
#pragma unroll
    for (int i = 0; i < 10; ++i) s = fmaf(w1[jj * 10 + i], qv[i], s);
    h[jj] = fmaxf(s, 0.f);
  }
#pragma unroll
  for (int o = 0; o < 10; ++o) {
    float s = b2[o];
#pragma unroll
    for (int jj = 0; jj < 32; ++jj) s = fmaf(w2[o * 32 + jj], h[jj], s);
    out[b * 10 + o] = s;
  }
}

// ---------------------------------------------------------------------------
extern "C" void kernel_launch(void* const* d_in, const int* in_sizes, int n_in,
                              void* d_out, int out_size, void* d_ws, size_t ws_size,
                              hipStream_t stream) {
  (void)in_sizes; (void)n_in; (void)out_size; (void)ws_size;
  const float* x    = (const float*)d_in[0];
  const float* c1w  = (const float*)d_in[1];
  const float* c1b  = (const float*)d_in[2];
  const float* bn1g = (const float*)d_in[3];
  const float* bn1b = (const float*)d_in[4];
  const float* c2w  = (const float*)d_in[5];
  const float* c2b  = (const float*)d_in[6];
  const float* bn2g = (const float*)d_in[7];
  const float* bn2b = (const float*)d_in[8];
  const float* fc1w = (const float*)d_in[9];
  const float* fc1b = (const float*)d_in[10];
  const float* selw = (const float*)d_in[11];
  const float* selb = (const float*)d_in[12];
  const float* qpar = (const float*)d_in[13];
  const float* p1w  = (const float*)d_in[14];
  const float* p1b  = (const float*)d_in[15];
  const float* p2w  = (const float*)d_in[16];
  const float* p2b  = (const float*)d_in[17];

  float* ws = (float*)d_ws;
  float* h1     = ws;                   // 2048*16*14*14 = 6,422,528
  float* h2     = h1 + 6422528;         // 2048*1568     = 3,211,264
  float* feats  = h2 + 3211264;         // 2048*784      = 1,605,632
  float* part1  = feats + 1605632;      // 2048*32
  float* part2  = part1 + 65536;        // 2048*64
  float* stats1 = part2 + 131072;       // 32
  float* stats2 = stats1 + 32;          // 64
  float* selv   = stats2 + 64;          // 20,480
  float* qout   = selv + 20480;         // 20,480
  float* outp   = (float*)d_out;

  k_conv1_stats<<<BATCH, 256, 0, stream>>>(x, c1w, c1b, part1);
  k_bnstat<<<16, 256, 0, stream>>>(part1, bn1g, bn1b, stats1, 16, BATCH,
                                   1.0 / (2048.0 * 784.0));
  k_conv1_fused<<<BATCH, 256, 0, stream>>>(x, c1w, c1b, stats1, h1);
  k_conv2<true><<<BATCH, 256, 0, stream>>>(h1, c2w, c2b, nullptr, part2, nullptr);
  k_bnstat<<<32, 256, 0, stream>>>(part2, bn2g, bn2b, stats2, 32, BATCH,
                                   1.0 / (2048.0 * 196.0));
  k_conv2<false><<<BATCH, 256, 0, stream>>>(h1, c2w, c2b, stats2, nullptr, h2);
  k_fc1<<<dim3(13, 32), 256, 0, stream>>>(h2, fc1w, fc1b, feats);
  k_sel<<<512, 256, 0, stream>>>(feats, selw, selb, selv);
  k_quantum<<<512, 256, 0, stream>>>(selv, qpar, qout);
  k_post<<<8, 256, 0, stream>>>(qout, p1w, p1b, p2w, p2b, outp);
}

// Round 2
// 212.246 us; speedup vs baseline: 1.5647x; 1.5647x over previous
//
#include <hip/hip_runtime.h>
#include <math.h>

// ---------------------------------------------------------------------------
// AngleEncodingQuantumNet: conv1+BN+relu+pool -> conv2+BN+relu+pool -> fc1
// (tanh) -> sel -> 10-qubit RY/CZ circuit -> post1(relu) -> post2.
// Train-mode BN => stats pass then apply pass. conv2 stores raw output when
// ws_size allows (skips the conv recompute). fc1 runs as bf16 MFMA with
// split-precision A (K' = 2x1568): C = Ah*Bh + Al*Bh; dropped A*Bl term is
// ~2^-9 relative weight noise, damped to ~2e-6 at the output (thr 3.8e-5).
// ---------------------------------------------------------------------------

#define BATCH 2048
#define PI_F 3.14159265358979323846f
#define KP 3200          // padded K' = 2*1568 -> 3200 (50 BK=64 steps)
#define KSTEPS 50

typedef unsigned short ushort_t;
typedef __attribute__((ext_vector_type(8))) short bf16x8;
typedef __attribute__((ext_vector_type(4))) float f32x4;

__device__ __forceinline__ float wave_reduce_add(float v) {
#pragma unroll
  for (int off = 32; off >= 1; off >>= 1) v += __shfl_xor(v, off, 64);
  return v;
}

__device__ __forceinline__ ushort_t f2bf(float v) {  // RNE f32 -> bf16 bits
  unsigned u = __float_as_uint(v);
  u += 0x7FFFu + ((u >> 16) & 1u);
  return (ushort_t)(u >> 16);
}
__device__ __forceinline__ float bf2f(ushort_t b) {
  return __uint_as_float(((unsigned)b) << 16);
}

// ---------------- conv1: stats pass ----------------------------------------
__global__ __launch_bounds__(256) void k_conv1_stats(
    const float* __restrict__ x, const float* __restrict__ cw,
    const float* __restrict__ cb, float* __restrict__ part1) {
  const int b = blockIdx.x;
  const int t = threadIdx.x;
  __shared__ float xs[30][33];
  __shared__ float ws[160];
  __shared__ float redS[16][28];
  __shared__ float redQ[16][28];
  for (int i = t; i < 30 * 33; i += 256) (&xs[0][0])[i] = 0.f;
  if (t < 144) ws[t] = cw[t];
  else if (t < 160) ws[t] = cb[t - 144];
  __syncthreads();
  const float* xb = x + b * 784;
  for (int i = t; i < 784; i += 256) xs[1 + i / 28][1 + (i % 28)] = xb[i];
  __syncthreads();
  for (int task = t; task < 448; task += 256) {
    const int oc = task / 28;
    const int row = task - oc * 28;
    float wk[9];
#pragma unroll
    for (int k = 0; k < 9; ++k) wk[k] = ws[oc * 9 + k];
    const float bc = ws[144 + oc];
    float A0 = xs[row][0], A1 = xs[row][1];
    float B0 = xs[row + 1][0], B1 = xs[row + 1][1];
    float C0 = xs[row + 2][0], C1 = xs[row + 2][1];
    float s = 0.f, q = 0.f;
#pragma unroll 4
    for (int xx = 0; xx < 28; ++xx) {
      float A2 = xs[row][xx + 2], B2 = xs[row + 1][xx + 2], C2 = xs[row + 2][xx + 2];
      float acc = bc;
      acc = fmaf(wk[0], A0, acc); acc = fmaf(wk[1], A1, acc); acc = fmaf(wk[2], A2, acc);
      acc = fmaf(wk[3], B0, acc); acc = fmaf(wk[4], B1, acc); acc = fmaf(wk[5], B2, acc);
      acc = fmaf(wk[6], C0, acc); acc = fmaf(wk[7], C1, acc); acc = fmaf(wk[8], C2, acc);
      s += acc; q = fmaf(acc, acc, q);
      A0 = A1; A1 = A2; B0 = B1; B1 = B2; C0 = C1; C1 = C2;
    }
    redS[oc][row] = s;
    redQ[oc][row] = q;
  }
  __syncthreads();
  if (t < 32) {
    const int c = t >> 1;
    float acc = 0.f;
    if (t & 1) {
#pragma unroll 4
      for (int r = 0; r < 28; ++r) acc += redQ[c][r];
    } else {
#pragma unroll 4
      for (int r = 0; r < 28; ++r) acc += redS[c][r];
    }
    part1[b * 32 + t] = acc;
  }
}

// ---------------- BN stats fold (both layers) -------------------------------
__global__ __launch_bounds__(256) void k_bnstat(
    const float* __restrict__ part, const float* __restrict__ g,
    const float* __restrict__ bb, float* __restrict__ stats,
    int nch, int nblk, double invN) {
  const int c = blockIdx.x;
  const int t = threadIdx.x;
  const int stride = nch * 2;
  double ls = 0.0, lq = 0.0;
  for (int i = t; i < nblk; i += 256) {
    ls += (double)part[i * stride + c * 2];
    lq += (double)part[i * stride + c * 2 + 1];
  }
#pragma unroll
  for (int off = 32; off >= 1; off >>= 1) {
    ls += __shfl_xor(ls, off, 64);
    lq += __shfl_xor(lq, off, 64);
  }
  __shared__ double rs[4], rq[4];
  if ((t & 63) == 0) { rs[t >> 6] = ls; rq[t >> 6] = lq; }
  __syncthreads();
  if (t == 0) {
    double S = rs[0] + rs[1] + rs[2] + rs[3];
    double Q = rq[0] + rq[1] + rq[2] + rq[3];
    double mean = S * invN;
    double var = Q * invN - mean * mean;
    double inv = 1.0 / sqrt(var + 1e-5);
    double sc = (double)g[c] * inv;
    stats[c * 2] = (float)sc;
    stats[c * 2 + 1] = (float)((double)bb[c] - mean * sc);
  }
}

// ---------------- conv1: fused BN+relu+pool pass ----------------------------
__global__ __launch_bounds__(256) void k_conv1_fused(
    const float* __restrict__ x, const float* __restrict__ cw,
    const float* __restrict__ cb, const float* __restrict__ stats1,
    float* __restrict__ h1) {
  const int b = blockIdx.x;
  const int t = threadIdx.x;
  __shared__ float xs[30][33];
  __shared__ float ws[160];
  for (int i = t; i < 30 * 33; i += 256) (&xs[0][0])[i] = 0.f;
  if (t < 144) ws[t] = cw[t];
  else if (t < 160) ws[t] = cb[t - 144];
  __syncthreads();
  const float* xb = x + b * 784;
  for (int i = t; i < 784; i += 256) xs[1 + i / 28][1 + (i % 28)] = xb[i];
  __syncthreads();
  if (t < 224) {
    const int oc = t / 14;
    const int pr = t - oc * 14;
    float wk[9];
#pragma unroll
    for (int k = 0; k < 9; ++k) wk[k] = ws[oc * 9 + k];
    const float bc = ws[144 + oc];
    const float scale = stats1[oc * 2], shift = stats1[oc * 2 + 1];
    const int r0 = 2 * pr;
    float A0 = xs[r0][0],     A1 = xs[r0][1];
    float B0 = xs[r0 + 1][0], B1 = xs[r0 + 1][1];
    float C0 = xs[r0 + 2][0], C1 = xs[r0 + 2][1];
    float D0 = xs[r0 + 3][0], D1 = xs[r0 + 3][1];
    float* hout = h1 + ((b * 16 + oc) * 14 + pr) * 14;
    float pmax = 0.f;
#pragma unroll 4
    for (int xx = 0; xx < 28; ++xx) {
      float A2 = xs[r0][xx + 2], B2 = xs[r0 + 1][xx + 2];
      float C2 = xs[r0 + 2][xx + 2], D2 = xs[r0 + 3][xx + 2];
      float c0 = bc, c1 = bc;
      c0 = fmaf(wk[0], A0, c0); c0 = fmaf(wk[1], A1, c0); c0 = fmaf(wk[2], A2, c0);
      c0 = fmaf(wk[3], B0, c0); c0 = fmaf(wk[4], B1, c0); c0 = fmaf(wk[5], B2, c0);
      c0 = fmaf(wk[6], C0, c0); c0 = fmaf(wk[7], C1, c0); c0 = fmaf(wk[8], C2, c0);
      c1 = fmaf(wk[0], B0, c1); c1 = fmaf(wk[1], B1, c1); c1 = fmaf(wk[2], B2, c1);
      c1 = fmaf(wk[3], C0, c1); c1 = fmaf(wk[4], C1, c1); c1 = fmaf(wk[5], C2, c1);
      c1 = fmaf(wk[6], D0, c1); c1 = fmaf(wk[7], D1, c1); c1 = fmaf(wk[8], D2, c1);
      float e0 = fmaxf(fmaf(scale, c0, shift), 0.f);
      float e1 = fmaxf(fmaf(scale, c1, shift), 0.f);
      float m = fmaxf(e0, e1);
      if ((xx & 1) == 0) pmax = m;
      else hout[xx >> 1] = fmaxf(pmax, m);
      A0 = A1; A1 = A2; B0 = B1; B1 = B2; C0 = C1; C1 = C2; D0 = D1; D1 = D2;
    }
  }
}

// ---------------- conv2 (template: stats pass / fused pass) -----------------
template <bool STATS>
__global__ __launch_bounds__(256, 2) void k_conv2(
    const float* __restrict__ h1, const float* __restrict__ cw,
    const float* __restrict__ cb, const float* __restrict__ stats2,
    float* __restrict__ part2, float* __restrict__ h2,
    float* __restrict__ rawout) {
  const int b = blockIdx.x;
  const int t = threadIdx.x;
  __shared__ float ins[16 * 16 * 20];
  __shared__ float w4[16 * 32 * 12];
  __shared__ float red[64];
  for (int i = t; i < 16 * 16 * 20; i += 256) ins[i] = 0.f;
  for (int i = t; i < 16 * 32 * 12; i += 256) w4[i] = 0.f;
  __syncthreads();
  const float* h1b = h1 + b * 3136;
  for (int i = t; i < 3136; i += 256) {
    int ic = i / 196, p = i - ic * 196;
    int y = p / 14, xx = p - y * 14;
    ins[(ic * 16 + 1 + y) * 20 + 1 + xx] = h1b[i];
  }
  for (int i = t; i < 4608; i += 256) {
    int ic = i / 288, jj = i - ic * 288;
    int oc = jj / 9, k = jj - oc * 9;
    w4[(ic * 32 + oc) * 12 + k] = cw[oc * 144 + ic * 9 + k];
  }
  __syncthreads();
  const int oc = t >> 3;
  const int j = t & 7;
  const float bc = cb[oc];
  float v0[14], v1[14];
#pragma unroll
  for (int i = 0; i < 14; ++i) { v0[i] = bc; v1[i] = bc; }
  if (j < 7) {
    const int rbase = 2 * j;
    for (int ic = 0; ic < 16; ++ic) {
      const float4* wp = (const float4*)&w4[(ic * 32 + oc) * 12];
      float4 wa = wp[0], wb = wp[1], wc = wp[2];
      float wk[9] = {wa.x, wa.y, wa.z, wa.w, wb.x, wb.y, wb.z, wb.w, wc.x};
      const float* rowp = &ins[(ic * 16 + rbase) * 20];
      float R0[16], R1[16], R2[16], R3[16];
#pragma unroll
      for (int q = 0; q < 4; ++q) {
        *(float4*)&R0[q * 4] = ((const float4*)(rowp))[q];
        *(float4*)&R1[q * 4] = ((const float4*)(rowp + 20))[q];
        *(float4*)&R2[q * 4] = ((const float4*)(rowp + 40))[q];
        *(float4*)&R3[q * 4] = ((const float4*)(rowp + 60))[q];
      }
#pragma unroll
      for (int xx = 0; xx < 14; ++xx) {
        float a0 = v0[xx], a1 = v1[xx];
        a0 = fmaf(wk[0], R0[xx], a0); a0 = fmaf(wk[1], R0[xx + 1], a0); a0 = fmaf(wk[2], R0[xx + 2], a0);
        a0 = fmaf(wk[3], R1[xx], a0); a0 = fmaf(wk[4], R1[xx + 1], a0); a0 = fmaf(wk[5], R1[xx + 2], a0);
        a0 = fmaf(wk[6], R2[xx], a0); a0 = fmaf(wk[7], R2[xx + 1], a0); a0 = fmaf(wk[8], R2[xx + 2], a0);
        a1 = fmaf(wk[0], R1[xx], a1); a1 = fmaf(wk[1], R1[xx + 1], a1); a1 = fmaf(wk[2], R1[xx + 2], a1);
        a1 = fmaf(wk[3], R2[xx], a1); a1 = fmaf(wk[4], R2[xx + 1], a1); a1 = fmaf(wk[5], R2[xx + 2], a1);
        a1 = fmaf(wk[6], R3[xx], a1); a1 = fmaf(wk[7], R3[xx + 1], a1); a1 = fmaf(wk[8], R3[xx + 2], a1);
        v0[xx] = a0; v1[xx] = a1;
      }
    }
  }
  if (STATS) {
    if (rawout != nullptr && j < 7) {
      float* rp = rawout + ((size_t)(b * 32 + oc) * 14 + 2 * j) * 14;
#pragma unroll
      for (int i = 0; i < 14; ++i) { rp[i] = v0[i]; rp[14 + i] = v1[i]; }
    }
    float s = 0.f, q = 0.f;
    if (j < 7) {
#pragma unroll
      for (int i = 0; i < 14; ++i) {
        s += v0[i] + v1[i];
        q = fmaf(v0[i], v0[i], q);
        q = fmaf(v1[i], v1[i], q);
      }
    }
#pragma unroll
    for (int off = 1; off <= 4; off <<= 1) {
      s += __shfl_xor(s, off, 64);
      q += __shfl_xor(q, off, 64);
    }
    if (j == 0) { red[oc * 2] = s; red[oc * 2 + 1] = q; }
    __syncthreads();
    if (t < 64) part2[b * 64 + t] = red[t];
  } else {
    if (j < 7) {
      const float scale = stats2[oc * 2], shift = stats2[oc * 2 + 1];
      float* hp = h2 + b * 1568 + oc * 49 + j * 7;
#pragma unroll
      for (int px = 0; px < 7; ++px) {
        float e00 = fmaxf(fmaf(scale, v0[2 * px], shift), 0.f);
        float e01 = fmaxf(fmaf(scale, v0[2 * px + 1], shift), 0.f);
        float e10 = fmaxf(fmaf(scale, v1[2 * px], shift), 0.f);
        float e11 = fmaxf(fmaf(scale, v1[2 * px + 1], shift), 0.f);
        hp[px] = fmaxf(fmaxf(e00, e01), fmaxf(e10, e11));
      }
    }
  }
}

// ---------------- pack A': [Ah | Al] bf16, logical layout, pad to KP --------
// raw mode: BN+relu+pool from raw conv2 output (BN monotone: pool first).
__global__ __launch_bounds__(256) void k_pack_a(
    const float* __restrict__ h2, const float* __restrict__ raw,
    const float* __restrict__ stats2, ushort_t* __restrict__ Ap) {
  const int m = blockIdx.x, t = threadIdx.x;
  __shared__ float hv[1568];
  if (raw != nullptr) {
    for (int i = t; i < 1568; i += 256) {
      int oc = i / 49, r = i - oc * 49;
      int py = r / 7, px = r - py * 7;
      const float* rp = raw + ((size_t)(m * 32 + oc) * 14 + 2 * py) * 14 + 2 * px;
      float mx = fmaxf(fmaxf(rp[0], rp[1]), fmaxf(rp[14], rp[15]));
      float mn = fminf(fminf(rp[0], rp[1]), fminf(rp[14], rp[15]));
      float sc = stats2[oc * 2], sh = stats2[oc * 2 + 1];
      hv[i] = fmaxf(fmaf(sc, (sc >= 0.f ? mx : mn), sh), 0.f);
    }
  } else {
    for (int i = t; i < 1568; i += 256) hv[i] = h2[(size_t)m * 1568 + i];
  }
  __syncthreads();
  ushort_t* ap = Ap + (size_t)m * KP;
  for (int c = t; c < KP / 8; c += 256) {
    union { ushort_t u[8]; uint4 v; } o;
    if (c < 196) {
#pragma unroll
      for (int j = 0; j < 8; ++j) o.u[j] = f2bf(hv[c * 8 + j]);
    } else if (c < 392) {
#pragma unroll
      for (int j = 0; j < 8; ++j) {
        float v = hv[(c - 196) * 8 + j];
        o.u[j] = f2bf(v - bf2f(f2bf(v)));
      }
    } else {
      o.v = make_uint4(0, 0, 0, 0);
    }
    *(uint4*)(ap + c * 8) = o.v;
  }
}

// ---------------- pack B': [Bh | Bh] bf16, rows padded to 832 ---------------
__global__ __launch_bounds__(256) void k_pack_b(
    const float* __restrict__ w, ushort_t* __restrict__ Bp) {
  const int n = blockIdx.x, t = threadIdx.x;
  ushort_t* bp = Bp + (size_t)n * KP;
  if (t < 196) {
    union { ushort_t u[8]; uint4 v; } o;
    o.v = make_uint4(0, 0, 0, 0);
    if (n < 784) {
      const float* wp = w + (size_t)n * 1568 + t * 8;
#pragma unroll
      for (int j = 0; j < 8; ++j) o.u[j] = f2bf(wp[j]);
    }
    *(uint4*)(bp + t * 8) = o.v;
    *(uint4*)(bp + 1568 + t * 8) = o.v;
  } else if (t < 204) {
    *(uint4*)(bp + 3136 + (t - 196) * 8) = make_uint4(0, 0, 0, 0);
  }
}

// ---------------- fc1 as bf16 MFMA GEMM + tanh ------------------------------
// C[2048x784] = A'[2048xKP] x B'[832xKP]^T. 64x64 tiles, BK=64, 4 waves,
// wave tile 32x32 (2x2 frags of 16x16x32). LDS XOR-swizzled (T2): phys slot
// = logical_slot ^ (row&7) kills the 16-way stride-128B conflict.
__global__ __launch_bounds__(256) void k_fc1_mfma(
    const ushort_t* __restrict__ Ap, const ushort_t* __restrict__ Bp,
    const float* __restrict__ bias, float* __restrict__ feats) {
  __shared__ ushort_t As[64 * 64];
  __shared__ ushort_t Bs[64 * 64];
  const int t = threadIdx.x;
  const int id = blockIdx.x;
  const int swz = (id & 7) * 52 + (id >> 3);  // 416 = 8*52: XCD-contig chunks
  const int mt = swz & 31, nt = swz >> 5;
  const int m0 = mt * 64, n0 = nt * 64;
  const int lane = t & 63, wid = t >> 6;
  const int wm = wid >> 1, wn = wid & 1;

  // staging: thread t handles (row=t>>3, slot=t&7) and (row+32, slot)
  const int srow = t >> 3, sslot = t & 7;
  const int xsl = (sslot ^ (srow & 7)) << 3;  // (row+32)&7 == row&7
  ushort_t* awp = &As[srow * 64 + xsl];
  ushort_t* bwp = &Bs[srow * 64 + xsl];
  const uint4* agp = (const uint4*)(Ap + (size_t)(m0 + srow) * KP) + sslot;
  const uint4* bgp = (const uint4*)(Bp + (size_t)(n0 + srow) * KP) + sslot;
  const int ROWOFF = 32 * (KP / 8);  // +32 rows, in uint4

  // frag read offsets (ushort units); r&7 == lane&7 since tiles are 16/32-mult
  const int rbaseA = (wm * 32 + (lane & 15)) * 64;
  const int rbaseB = (wn * 32 + (lane & 15)) * 64;
  const int x0 = (((lane >> 4) + 0) ^ (lane & 7)) << 3;
  const int x1 = (((lane >> 4) + 4) ^ (lane & 7)) << 3;

  f32x4 acc00 = {0.f, 0.f, 0.f, 0.f};
  f32x4 acc01 = acc00, acc10 = acc00, acc11 = acc00;

  uint4 ca0 = agp[0], ca1 = agp[ROWOFF];
  uint4 cb0 = bgp[0], cb1 = bgp[ROWOFF];
  for (int kt = 0; kt < KSTEPS; ++kt) {
    __syncthreads();
    *(uint4*)awp = ca0; *(uint4*)(awp + 32 * 64) = ca1;
    *(uint4*)bwp = cb0; *(uint4*)(bwp + 32 * 64) = cb1;
    __syncthreads();
    uint4 na0 = ca0, na1 = ca1, nb0 = cb0, nb1 = cb1;
    if (kt < KSTEPS - 1) {  // prefetch next tile; hides HBM/L2 under MFMA
      const uint4* ag = agp + (kt + 1) * 8;
      const uint4* bg = bgp + (kt + 1) * 8;
      na0 = ag[0]; na1 = ag[ROWOFF]; nb0 = bg[0]; nb1 = bg[ROWOFF];
    }
    {
      bf16x8 a0 = *(const bf16x8*)&As[rbaseA + x0];
      bf16x8 a1 = *(const bf16x8*)&As[rbaseA + 1024 + x0];
      bf16x8 b0 = *(const bf16x8*)&Bs[rbaseB + x0];
      bf16x8 b1 = *(const bf16x8*)&Bs[rbaseB + 1024 + x0];
      acc00 = __builtin_amdgcn_mfma_f32_16x16x32_bf16(a0, b0, acc00, 0, 0, 0);
      acc01 = __builtin_amdgcn_mfma_f32_16x16x32_bf16(a0, b1, acc01, 0, 0, 0);
      acc10 = __builtin_amdgcn_mfma_f32_16x16x32_bf16(a1, b0, acc10, 0, 0, 0);
      acc11 = __builtin_amdgcn_mfma_f32_16x16x32_bf16(a1, b1, acc11, 0, 0, 0);
    }
    {
      bf16x8 a0 = *(const bf16x8*)&As[rbaseA + x1];
      bf16x8 a1 = *(const bf16x8*)&As[rbaseA + 1024 + x1];
      bf16x8 b0 = *(const bf16x8*)&Bs[rbaseB + x1];
      bf16x8 b1 = *(const bf16x8*)&Bs[rbaseB + 1024 + x1];
      acc00 = __builtin_amdgcn_mfma_f32_16x16x32_bf16(a0, b0, acc00, 0, 0, 0);
      acc01 = __builtin_amdgcn_mfma_f32_16x16x32_bf16(a0, b1, acc01, 0, 0, 0);
      acc10 = __builtin_amdgcn_mfma_f32_16x16x32_bf16(a1, b0, acc10, 0, 0, 0);
      acc11 = __builtin_amdgcn_mfma_f32_16x16x32_bf16(a1, b1, acc11, 0, 0, 0);
    }
    ca0 = na0; ca1 = na1; cb0 = nb0; cb1 = nb1;
  }

  // epilogue: C/D layout col=lane&15 (n), row=(lane>>4)*4+reg (m)  [m89]
  const int nbase = n0 + wn * 32 + (lane & 15);
  const int mbase = m0 + wm * 32 + ((lane >> 4) << 2);
  auto emit = [&](f32x4 v, int fm, int fn) {
    const int n = nbase + fn * 16;
    if (n < 784) {
      const float bv = bias[n];
      const int mr = mbase + fm * 16;
#pragma unroll
      for (int r = 0; r < 4; ++r)
        feats[(size_t)(mr + r) * 784 + n] = tanhf(v[r] + bv);
    }
  };
  emit(acc00, 0, 0); emit(acc01, 0, 1); emit(acc10, 1, 0); emit(acc11, 1, 1);
}

// ---------------- sel: feats[2048][784] @ sel_w[10][784]^T + b --------------
__global__ __launch_bounds__(256) void k_sel(
    const float* __restrict__ feats, const float* __restrict__ sw,
    const float* __restrict__ sb, float* __restrict__ selv) {
  const int wid = (blockIdx.x << 2) + (threadIdx.x >> 6);
  const int lane = threadIdx.x & 63;
  const float* f = feats + (size_t)wid * 784;
  float acc[10];
#pragma unroll
  for (int i = 0; i < 10; ++i) acc[i] = 0.f;
  for (int k = lane; k < 784; k += 64) {
    const float fv = f[k];
#pragma unroll
    for (int i = 0; i < 10; ++i) acc[i] = fmaf(fv, sw[i * 784 + k], acc[i]);
  }
#pragma unroll
  for (int i = 0; i < 10; ++i) acc[i] = wave_reduce_add(acc[i]);
  if (lane == 0) {
#pragma unroll
    for (int i = 0; i < 10; ++i) selv[wid * 10 + i] = acc[i] + sb[i];
  }
}

// ---------------- 10-qubit statevector circuit ------------------------------
template <int W>
__device__ __forceinline__ void ry_gate(float (&a)[16], int lane, float th) {
  float s, c;
  sincosf(0.5f * th, &s, &c);
  if (W < 4) {
    const int st = 1 << W;
#pragma unroll
    for (int r = 0; r < 16; ++r) {
      if (!(r & st)) {
        float lo = a[r], hi = a[r + st];
        a[r] = fmaf(c, lo, -s * hi);
        a[r + st] = fmaf(s, lo, c * hi);
      }
    }
  } else {
    const int m = 1 << (W - 4);
    const float sg = (lane & m) ? s : -s;
#pragma unroll
    for (int r = 0; r < 16; ++r) {
      float other = __shfl_xor(a[r], m, 64);
      a[r] = fmaf(c, a[r], sg * other);
    }
  }
}

#define RY10(EXPR)                                                   \
  {                                                                  \
    ry_gate<0>(a, lane, EXPR(0)); ry_gate<1>(a, lane, EXPR(1));      \
    ry_gate<2>(a, lane, EXPR(2)); ry_gate<3>(a, lane, EXPR(3));      \
    ry_gate<4>(a, lane, EXPR(4)); ry_gate<5>(a, lane, EXPR(5));      \
    ry_gate<6>(a, lane, EXPR(6)); ry_gate<7>(a, lane, EXPR(7));      \
    ry_gate<8>(a, lane, EXPR(8)); ry_gate<9>(a, lane, EXPR(9));      \
  }

__global__ __launch_bounds__(256) void k_quantum(
    const float* __restrict__ selv, const float* __restrict__ qp,
    float* __restrict__ qout) {
  const int b = (blockIdx.x << 2) + (threadIdx.x >> 6);
  const int lane = threadIdx.x & 63;
  float a[16];
#pragma unroll
  for (int r = 0; r < 16; ++r) a[r] = 0.f;
  if (lane == 0) a[0] = 1.f;
  float czs[16];
#pragma unroll
  for (int r = 0; r < 16; ++r) {
    int idx = (lane << 4) | r;
    czs[r] = (__popc(idx & (idx >> 1)) & 1) ? -1.f : 1.f;
  }
  const float* sp = selv + b * 10;
#define ENC(i) (sp[i] * PI_F)
  RY10(ENC)
#undef ENC
  for (int layer = 0; layer < 3; ++layer) {
    const float* lp = qp + layer * 10;
#define LAY(i) (lp[i])
    RY10(LAY)
#undef LAY
#pragma unroll
    for (int r = 0; r < 16; ++r) a[r] *= czs[r];
  }
  float p[16];
  float lt = 0.f;
#pragma unroll
  for (int r = 0; r < 16; ++r) { p[r] = a[r] * a[r]; lt += p[r]; }
  float z[10];
#pragma unroll
  for (int w = 0; w < 4; ++w) {
    float v = 0.f;
#pragma unroll
    for (int r = 0; r < 16; ++r) v += ((r >> w) & 1) ? -p[r] : p[r];
    z[w] = v;
  }
#pragma unroll
  for (int w = 4; w < 10; ++w) z[w] = ((lane >> (w - 4)) & 1) ? -lt : lt;
#pragma unroll
  for (int w = 0; w < 10; ++w) z[w] = wave_reduce_add(z[w]);
  if (lane == 0) {
#pragma unroll
    for (int w = 0; w < 10; ++w) qout[b * 10 + w] = z[w];
  }
}

// ---------------- post layers ------------------------------------------------
__global__ __launch_bounds__(256) void k_post(
    const float* __restrict__ qout, const float* __restrict__ w1,
    const float* __restrict__ b1, const float* __restrict__ w2,
    const float* __restrict__ b2, float* __restrict__ out) {
  const int b = blockIdx.x * 256 + threadIdx.x;
  float qv[10];
#pragma unroll
  for (int i = 0; i < 10; ++i) qv[i] = qout[b * 10 + i];
  float h[32];
#pragma unroll
  for (int jj = 0; jj < 32; ++jj) {
    float s = b1[jj];
#pragma unroll
    for (int i = 0; i < 10; ++i) s = fmaf(w1[jj * 10 + i], qv[i], s);
    h[jj] = fmaxf(s, 0.f);
  }
#pragma unroll
  for (int o = 0; o < 10; ++o) {
    float s = b2[o];
#pragma unroll
    for (int jj = 0; jj < 32; ++jj) s = fmaf(w2[o * 32 + jj], h[jj], s);
    out[b * 10 + o] = s;
  }
}

// ---------------------------------------------------------------------------
extern "C" void kernel_launch(void* const* d_in, const int* in_sizes, int n_in,
                              void* d_out, int out_size, void* d_ws, size_t ws_size,
                              hipStream_t stream) {
  (void)in_sizes; (void)n_in; (void)out_size;
  const float* x    = (const float*)d_in[0];
  const float* c1w  = (const float*)d_in[1];
  const float* c1b  = (const float*)d_in[2];
  const float* bn1g = (const float*)d_in[3];
  const float* bn1b = (const float*)d_in[4];
  const float* c2w  = (const float*)d_in[5];
  const float* c2b  = (const float*)d_in[6];
  const float* bn2g = (const float*)d_in[7];
  const float* bn2b = (const float*)d_in[8];
  const float* fc1w = (const float*)d_in[9];
  const float* fc1b = (const float*)d_in[10];
  const float* selw = (const float*)d_in[11];
  const float* selb = (const float*)d_in[12];
  const float* qpar = (const float*)d_in[13];
  const float* p1w  = (const float*)d_in[14];
  const float* p1b  = (const float*)d_in[15];
  const float* p2w  = (const float*)d_in[16];
  const float* p2b  = (const float*)d_in[17];

  // ws layout (floats). A' (bf16) aliases h1 (h1 dead before pack_a runs).
  // raw path needs 22,442,080 f = 89.8 MB; fallback needs 51.2 MB.
  const bool use_raw = ws_size >= (size_t)89768320;
  float* ws = (float*)d_ws;
  float* h1 = ws;
  ushort_t* Ap = (ushort_t*)ws;  // 2048*3200 ushorts = 3,276,800 f < 6,422,528 f
  size_t o = 6422528;
  float* raw = nullptr;
  if (use_raw) { raw = ws + o; o += 12845056; }
  float* h2 = ws + o;
  if (!use_raw) o += 3211264;
  ushort_t* Bp = (ushort_t*)(ws + o); o += 1331200;  // 832*3200 ushorts
  float* feats  = ws + o; o += 1605632;
  float* part1  = ws + o; o += 65536;
  float* part2  = ws + o; o += 131072;
  float* stats1 = ws + o; o += 32;
  float* stats2 = ws + o; o += 64;
  float* selv   = ws + o; o += 20480;
  float* qout   = ws + o; o += 20480;
  float* outp   = (float*)d_out;

  k_conv1_stats<<<BATCH, 256, 0, stream>>>(x, c1w, c1b, part1);
  k_bnstat<<<16, 256, 0, stream>>>(part1, bn1g, bn1b, stats1, 16, BATCH,
                                   1.0 / (2048.0 * 784.0));
  k_conv1_fused<<<BATCH, 256, 0, stream>>>(x, c1w, c1b, stats1, h1);
  k_conv2<true><<<BATCH, 256, 0, stream>>>(h1, c2w, c2b, nullptr, part2,
                                           nullptr, raw);
  k_bnstat<<<32, 256, 0, stream>>>(part2, bn2g, bn2b, stats2, 32, BATCH,
                                   1.0 / (2048.0 * 196.0));
  if (!use_raw) {
    k_conv2<false><<<BATCH, 256, 0, stream>>>(h1, c2w, c2b, stats2, nullptr,
                                              h2, nullptr);
    k_pack_a<<<BATCH, 256, 0, stream>>>(h2, nullptr, stats2, Ap);
  } else {
    k_pack_a<<<BATCH, 256, 0, stream>>>(nullptr, raw, stats2, Ap);
  }
  k_pack_b<<<832, 256, 0, stream>>>(fc1w, Bp);
  k_fc1_mfma<<<416, 256, 0, stream>>>(Ap, Bp, fc1b, feats);
  k_sel<<<512, 256, 0, stream>>>(feats, selw, selb, selv);
  k_quantum<<<512, 256, 0, stream>>>(selv, qpar, qout);
  k_post<<<8, 256, 0, stream>>>(qout, p1w, p1b, p2w, p2b, outp);
}